// Round 6
// baseline (4127.868 us; speedup 1.0000x reference)
//
#include <hip/hip_runtime.h>
#include <hip/hip_bf16.h>
#include <stdint.h>

// Problem dims
#define BB 64
#define SS 512
#define EE 256
#define HH 512
#define NWG 32   // scan workgroups; each owns 16 hidden cols (x5 gates = 80 W cols)

typedef short s16x8 __attribute__((ext_vector_type(8)));
typedef int   v4i   __attribute__((ext_vector_type(4)));
typedef float vf4   __attribute__((ext_vector_type(4)));

// Workspace byte offsets (all 256B aligned). Total = 205,817,856 B (~196.3 MiB)
#define OFF_WBT   0UL           // W bf16 transposed [2560][768]
#define OFF_EMB   3932160UL     // embedding bf16 [100][256]
#define OFF_WIT   3983360UL     // Wi bf16 transposed+padded [112][512]
#define OFF_DTT   4098048UL     // time_deltas transposed f32 [512][64]
#define OFF_FLAGS 4229120UL     // (legacy flag region, still zeroed, unused by scan)
#define OFF_HBUF  4491264UL     // h bf16 [512][64][512] — zeroed each launch (memset)
#define OFF_ZXP   38045696UL    // zx bf16, MFMA-frag-permuted [512][32][4][5][64][4]

__device__ __forceinline__ unsigned short f2bf(float f) {
  unsigned u = __float_as_uint(f);
  u += 0x7fffu + ((u >> 16) & 1u);   // round-to-nearest-even
  return (unsigned short)(u >> 16);
}
__device__ __forceinline__ float bf2f(unsigned short h) {
  return __uint_as_float(((unsigned)h) << 16);
}
__device__ __forceinline__ float sigmoidf_(float x) { return 1.f / (1.f + __expf(-x)); }
__device__ __forceinline__ float softplusf_(float x) {
  return fmaxf(x, 0.f) + log1pf(__expf(-fabsf(x)));
}
__device__ __forceinline__ float tanhf_(float x) {   // overflow-safe
  float e = __expf(2.f * x);
  return 1.f - 2.f / (e + 1.f);
}
// classic "contains a zero halfword" bit trick
__device__ __forceinline__ unsigned haszero16(unsigned x) {
  return (x - 0x00010001u) & ~x & 0x80008000u;
}

// ---------------- init: dtype conversions / transposes / flag zeroing ----------------
__global__ void init_kernel(const float* __restrict__ W, const float* __restrict__ emb,
                            const float* __restrict__ Wi, const float* __restrict__ td,
                            unsigned short* __restrict__ WbT, unsigned short* __restrict__ embB,
                            unsigned short* __restrict__ WiT, float* __restrict__ dtT,
                            int* __restrict__ flags) {
  unsigned i = blockIdx.x * 256u + threadIdx.x;
  if (i < 1966080u) {               // WbT[c][k] = bf16(W[k][c])
    unsigned c = i / 768u, k = i % 768u;
    WbT[i] = f2bf(W[(size_t)k * 2560u + c]);
    return;
  }
  i -= 1966080u;
  if (i < 25600u) { embB[i] = f2bf(emb[i]); return; }
  i -= 25600u;
  if (i < 57344u) {                 // WiT[c][k] = bf16(Wi[k][c]), pad c=100..111 with 0
    unsigned c = i / 512u, k = i % 512u;
    WiT[i] = f2bf(c < 100u ? Wi[(size_t)k * 100u + c] : 0.f);
    return;
  }
  i -= 57344u;
  if (i < 32768u) {                 // dtT[t][b] = td[b][t]
    unsigned t = i / 64u, b = i % 64u;
    dtT[i] = td[(size_t)b * 512u + t];
    return;
  }
  i -= 32768u;
  if (i < 65536u) { flags[i] = 0; return; }
}

// ---------------- zx = gather(embedding) @ W_x + b, stored bf16 in frag-permuted layout ----
__global__ __launch_bounds__(256, 2)
void zx_kernel(const int* __restrict__ evt, const unsigned short* __restrict__ embB,
               const unsigned short* __restrict__ WbT, const float* __restrict__ bias,
               unsigned short* __restrict__ zxp) {
  const int t = blockIdx.y;
  const int tid = threadIdx.x;
  const int v = tid >> 6, lane = tid & 63;
  const int m = lane & 15, quad = lane >> 4;
  const int cbase = blockIdx.x * 256 + v * 64;  // wave's 64 output cols (4 frags)

  s16x8 Breg[8][4];
#pragma unroll
  for (int cf = 0; cf < 4; ++cf) {
    const unsigned short* bp = WbT + (size_t)(cbase + cf * 16 + m) * 768 + quad * 8;
#pragma unroll
    for (int ch = 0; ch < 8; ++ch) Breg[ch][cf] = *(const s16x8*)(bp + ch * 32);
  }
  int ev[4];
#pragma unroll
  for (int rt = 0; rt < 4; ++rt) ev[rt] = evt[(size_t)(rt * 16 + m) * 512 + t];

  vf4 acc[4][4];
#pragma unroll
  for (int cf = 0; cf < 4; ++cf) {
    float bbv = bias[cbase + cf * 16 + m];
#pragma unroll
    for (int rt = 0; rt < 4; ++rt) acc[rt][cf] = (vf4){bbv, bbv, bbv, bbv};
  }
#pragma unroll
  for (int ch = 0; ch < 8; ++ch) {
#pragma unroll
    for (int rt = 0; rt < 4; ++rt) {
      s16x8 a = *(const s16x8*)(embB + (size_t)ev[rt] * 256 + ch * 32 + quad * 8);
#pragma unroll
      for (int cf = 0; cf < 4; ++cf)
        acc[rt][cf] = __builtin_amdgcn_mfma_f32_16x16x32_bf16(a, Breg[ch][cf], acc[rt][cf], 0, 0, 0);
    }
  }
#pragma unroll
  for (int cf = 0; cf < 4; ++cf) {
    int col0 = cbase + cf * 16;
    int g = col0 >> 9;              // gate index
    int w = (col0 & 511) >> 4;      // scan WG owning these cols
#pragma unroll
    for (int rt = 0; rt < 4; ++rt) {
      unsigned h0 = f2bf(acc[rt][cf][0]);
      unsigned h1 = f2bf(acc[rt][cf][1]);
      unsigned h2 = f2bf(acc[rt][cf][2]);
      unsigned h3 = f2bf(acc[rt][cf][3]);
      uint2 val;
      val.x = h0 | (h1 << 16);
      val.y = h2 | (h3 << 16);
      ((uint2*)zxp)[((((size_t)t * 32 + w) * 4 + rt) * 5 + g) * 64 + lane] = val;
    }
  }
}

// ---------------- persistent sequential scan: 32 WGs, DATA-AS-SIGNAL sync ----------------
// Wave v of WG w owns batch rows [16v,16v+16) x hidden cols [16w,16w+16).
// hbuf is zeroed each launch (hipMemsetAsync); 0x0000 means "not yet written".
// Producer: gates -> map ±0 bf16 to 0x0001 (error 2^-133) -> agent-scope h-stores.
//   NO drain, NO flag: the data itself is the publication. (R5 lesson: producers
//   publish in lockstep, so the old drain->flag->observe->load chain was 4 serial
//   far hops per step with nothing to overlap; this collapses it to ~2.)
// Consumer: poll the h data with sc0 sc1 (L1/L2-bypass) dwordx4 loads — immune to
//   the R1 L1-staleness trap; each 2B element is written once, atomically, so
//   "all 8 halfwords nonzero" <=> chunk final (no torn values possible).
//   Insurance: after 4096 rounds fall back to per-dword agent atomic loads
//   (the baseline-verified-fresh primitive) — unconditional forward progress.
__global__ __launch_bounds__(256, 1)
void scan_kernel(const unsigned short* __restrict__ WbT,
                 const unsigned short* __restrict__ zxp,
                 const float* __restrict__ dtT,
                 unsigned short* __restrict__ hbuf,
                 float* __restrict__ out_h, float* __restrict__ out_d) {
  const int w = blockIdx.x;           // 0..31, owns hidden cols [w*16, w*16+16)
  const int tid = threadIdx.x;
  const int v = tid >> 6, lane = tid & 63;
  const int m = lane & 15, quad = lane >> 4;
  const int rowb = v * 16;
  const int bb0 = rowb + quad * 4;    // first batch row of this lane's C-frag elems
  const int col = w * 16 + m;         // hidden col of this lane's C-frag elems

  // W_h slice resident in registers: Breg[ch][g], k = 256 + ch*32 + quad*8 + j
  s16x8 Breg[16][5];
#pragma unroll
  for (int g = 0; g < 5; ++g) {
    const unsigned short* bp = WbT + (size_t)(g * 512 + w * 16 + m) * 768 + 256 + quad * 8;
#pragma unroll
    for (int ch = 0; ch < 16; ++ch) Breg[ch][g] = *(const s16x8*)(bp + ch * 32);
  }

  vf4 cst = (vf4){0.f, 0.f, 0.f, 0.f};   // cell state (4 rows x this lane's col)

  for (int t = 0; t < 512; ++t) {
    v4i areg[16];
    const unsigned short* hsrc =
        hbuf + (size_t)(t - 1) * (BB * HH) + (size_t)(rowb + m) * HH + quad * 8;
    if (t > 0) {
      // Issue all 16 bypass chunk loads as early as possible (fly under zx unpack).
#pragma unroll
      for (int ch = 0; ch < 16; ++ch) {
        const unsigned short* ap = hsrc + ch * 32;
        asm volatile("global_load_dwordx4 %0, %1, off sc0 sc1"
                     : "=v"(areg[ch]) : "v"(ap) : "memory");
      }
    }

    // acc init from zx (independent of recurrence)
    vf4 acc[5];
#pragma unroll
    for (int g = 0; g < 5; ++g) {
      uint2 zv = ((const uint2*)zxp)[((((size_t)t * 32 + w) * 4 + v) * 5 + g) * 64 + lane];
      acc[g][0] = bf2f((unsigned short)(zv.x & 0xffffu));
      acc[g][1] = bf2f((unsigned short)(zv.x >> 16));
      acc[g][2] = bf2f((unsigned short)(zv.y & 0xffffu));
      acc[g][3] = bf2f((unsigned short)(zv.y >> 16));
    }
    vf4 dt4 = *(const vf4*)(dtT + t * 64 + bb0);

    if (t > 0) {
      unsigned bad = 0xffffu;
      int it = 0;
      for (;;) {
        asm volatile("s_waitcnt vmcnt(0)" ::: "memory");
        __builtin_amdgcn_sched_barrier(0);   // rule #18: fence reg-only uses behind waitcnt
#pragma unroll
        for (int ch = 0; ch < 16; ++ch) {
          if (bad & (1u << ch)) {
            unsigned z = haszero16((unsigned)areg[ch][0]) | haszero16((unsigned)areg[ch][1]) |
                         haszero16((unsigned)areg[ch][2]) | haszero16((unsigned)areg[ch][3]);
            if (__all(z == 0u)) bad &= ~(1u << ch);
          }
        }
        if (!bad) break;
        ++it;
        if (it < 4096) {
#pragma unroll
          for (int ch = 0; ch < 16; ++ch) {
            if (bad & (1u << ch)) {
              const unsigned short* ap = hsrc + ch * 32;
              asm volatile("global_load_dwordx4 %0, %1, off sc0 sc1"
                           : "=v"(areg[ch]) : "v"(ap) : "memory");
            }
          }
        } else {
          // Fallback (hang-proof): per-dword agent atomic loads, verified-fresh.
#pragma unroll
          for (int ch = 0; ch < 16; ++ch) {
            if (bad & (1u << ch)) {
              const int* ap = (const int*)(hsrc + ch * 32);
#pragma unroll
              for (int d = 0; d < 4; ++d)
                areg[ch][d] = __hip_atomic_load(ap + d, __ATOMIC_RELAXED,
                                                __HIP_MEMORY_SCOPE_AGENT);
            }
          }
        }
      }
      __builtin_amdgcn_sched_barrier(0);
#pragma unroll
      for (int ch = 0; ch < 16; ++ch) {
        s16x8 a = __builtin_bit_cast(s16x8, areg[ch]);
#pragma unroll
        for (int g = 0; g < 5; ++g)
          acc[g] = __builtin_amdgcn_mfma_f32_16x16x32_bf16(a, Breg[ch][g], acc[g], 0, 0, 0);
      }
    }

    // gates + state update; h-store IS the publication (fire-and-forget).
    float hv[4], dv[4];
#pragma unroll
    for (int r = 0; r < 4; ++r) {
      float i_ = sigmoidf_(acc[0][r]);
      float f_ = sigmoidf_(acc[1][r]);
      float o_ = sigmoidf_(acc[2][r]);
      float g_ = tanhf_(acc[3][r]);
      float dec = softplusf_(acc[4][r]);
      float cn = f_ * cst[r] + i_ * g_;
      float ct = cn * __expf(-dec * dt4[r]);
      float h_ = o_ * tanhf_(ct);
      cst[r] = ct;
      hv[r] = h_; dv[r] = dec;
      unsigned short hb = f2bf(h_);
      if ((hb & 0x7fffu) == 0u) hb |= 1u;   // never store the ±0 bit pattern (sentinel)
      __hip_atomic_store(hbuf + (size_t)t * (BB * HH) + (size_t)(bb0 + r) * HH + col,
                         hb, __ATOMIC_RELAXED, __HIP_MEMORY_SCOPE_AGENT);
    }
    // Off-critical-path fp32 outputs.
#pragma unroll
    for (int r = 0; r < 4; ++r) {
      size_t oo = ((size_t)(bb0 + r) * SS + t) * HH + col;
      out_h[oo] = hv[r];
      out_d[oo] = dv[r];
    }
  }
}

// ---------------- base_intensities = softplus(h @ Wi + bi) ----------------
__global__ __launch_bounds__(256, 2)
void inten_kernel(const unsigned short* __restrict__ hbuf,
                  const unsigned short* __restrict__ WiT,
                  const float* __restrict__ bi,
                  float* __restrict__ out_i) {
  const int b = blockIdx.y;            // batch row
  const int t0 = blockIdx.x * 64;      // 64 timesteps per WG
  const int tid = threadIdx.x;
  const int v = tid >> 6, lane = tid & 63;
  const int m = lane & 15, quad = lane >> 4;
  const int trow = t0 + v * 16 + m;    // A row = timestep

  vf4 acc[7];
#pragma unroll
  for (int cf = 0; cf < 7; ++cf) {
    int c = cf * 16 + m;
    float bbv = (c < 100) ? bi[c] : 0.f;
    acc[cf] = (vf4){bbv, bbv, bbv, bbv};
  }
  const unsigned short* ha = hbuf + ((size_t)trow * 64 + b) * 512 + quad * 8;
#pragma unroll 4
  for (int ch = 0; ch < 16; ++ch) {
    s16x8 a = *(const s16x8*)(ha + ch * 32);
#pragma unroll
    for (int cf = 0; cf < 7; ++cf) {
      s16x8 bf = *(const s16x8*)(WiT + (size_t)(cf * 16 + m) * 512 + ch * 32 + quad * 8);
      acc[cf] = __builtin_amdgcn_mfma_f32_16x16x32_bf16(a, bf, acc[cf], 0, 0, 0);
    }
  }
#pragma unroll
  for (int cf = 0; cf < 7; ++cf) {
    int c = cf * 16 + m;
#pragma unroll
    for (int r = 0; r < 4; ++r) {
      int tt = t0 + v * 16 + quad * 4 + r;
      if (c < 100) out_i[((size_t)b * 512 + tt) * 100 + c] = softplusf_(acc[cf][r]);
    }
  }
}

extern "C" void kernel_launch(void* const* d_in, const int* in_sizes, int n_in,
                              void* d_out, int out_size, void* d_ws, size_t ws_size,
                              hipStream_t stream) {
  (void)in_sizes; (void)n_in; (void)out_size; (void)ws_size;
  const int*   evt  = (const int*)d_in[0];
  const float* td   = (const float*)d_in[1];
  const float* emb  = (const float*)d_in[2];
  const float* W    = (const float*)d_in[3];
  const float* bias = (const float*)d_in[4];
  const float* Wi   = (const float*)d_in[5];
  const float* bi   = (const float*)d_in[6];

  char* ws = (char*)d_ws;
  unsigned short* WbT  = (unsigned short*)(ws + OFF_WBT);
  unsigned short* embB = (unsigned short*)(ws + OFF_EMB);
  unsigned short* WiT  = (unsigned short*)(ws + OFF_WIT);
  float*          dtT  = (float*)(ws + OFF_DTT);
  int*            flags= (int*)(ws + OFF_FLAGS);
  unsigned short* hbuf = (unsigned short*)(ws + OFF_HBUF);
  unsigned short* zxp  = (unsigned short*)(ws + OFF_ZXP);

  float* out_h = (float*)d_out;
  float* out_d = out_h + (size_t)BB * SS * HH;
  float* out_i = out_d + (size_t)BB * SS * HH;

  init_kernel<<<8388, 256, 0, stream>>>(W, emb, Wi, td, WbT, embB, WiT, dtT, flags);
  // hbuf = 0 each launch: 0x0000 is the "not yet written" sentinel for data-as-signal.
  hipMemsetAsync(hbuf, 0, (size_t)SS * BB * HH * sizeof(unsigned short), stream);
  zx_kernel<<<dim3(10, 512), 256, 0, stream>>>(evt, embB, WbT, bias, zxp);
  scan_kernel<<<NWG, 256, 0, stream>>>(WbT, zxp, dtT, hbuf, out_h, out_d);
  inten_kernel<<<dim3(8, 64), 256, 0, stream>>>(hbuf, WiT, bi, out_i);
}

// Round 7
// 3707.076 us; speedup vs baseline: 1.1135x; 1.1135x over previous
//
#include <hip/hip_runtime.h>
#include <hip/hip_bf16.h>
#include <stdint.h>

// Problem dims
#define BB 64
#define SS 512
#define EE 256
#define HH 512
#define NWG 32   // scan workgroups; each owns 16 hidden cols (x5 gates = 80 W cols)

typedef short s16x8 __attribute__((ext_vector_type(8)));
typedef float vf4 __attribute__((ext_vector_type(4)));

// Workspace byte offsets (all 256B aligned). Total = 205,817,856 B (~196.3 MiB)
#define OFF_WBT   0UL           // W bf16 transposed [2560][768]
#define OFF_EMB   3932160UL     // embedding bf16 [100][256]
#define OFF_WIT   3983360UL     // Wi bf16 transposed+padded [112][512]
#define OFF_DTT   4098048UL     // time_deltas transposed f32 [512][64]
#define OFF_FLAGS 4229120UL     // int flags, 65536 dwords: [t][v][w] -> 32 consecutive dwords per (t,v)
#define OFF_HBUF  4491264UL     // h bf16 [512][64][512]
#define OFF_ZXP   38045696UL    // zx bf16, MFMA-frag-permuted [512][32][4][5][64][4]

// COALESCED flag layout (R6 lesson): all 32 producer flags of a (t, v) group are
// 32 consecutive dwords (128 B = 2 lines). One 32-lane poll = ONE coalesced load
// touching 2 L3 lines, vs the old line-sharded layout's 32 separate line
// transactions per poll iteration (~80K L3 accesses/step of pure poll traffic —
// the suspected latency inflater). Producers store distinct dwords (no RMW).
__device__ __forceinline__ int fidx(int t, int v, int w) {
  return ((t * 4 + v) << 5) + w;     // max (511*4+3)*32+31 = 65535 < 65536
}

__device__ __forceinline__ unsigned short f2bf(float f) {
  unsigned u = __float_as_uint(f);
  u += 0x7fffu + ((u >> 16) & 1u);   // round-to-nearest-even
  return (unsigned short)(u >> 16);
}
__device__ __forceinline__ float bf2f(unsigned short h) {
  return __uint_as_float(((unsigned)h) << 16);
}
__device__ __forceinline__ float sigmoidf_(float x) { return 1.f / (1.f + __expf(-x)); }
__device__ __forceinline__ float softplusf_(float x) {
  return fmaxf(x, 0.f) + log1pf(__expf(-fabsf(x)));
}
__device__ __forceinline__ float tanhf_(float x) {   // overflow-safe
  float e = __expf(2.f * x);
  return 1.f - 2.f / (e + 1.f);
}

// ---------------- init: dtype conversions / transposes / flag zeroing ----------------
__global__ void init_kernel(const float* __restrict__ W, const float* __restrict__ emb,
                            const float* __restrict__ Wi, const float* __restrict__ td,
                            unsigned short* __restrict__ WbT, unsigned short* __restrict__ embB,
                            unsigned short* __restrict__ WiT, float* __restrict__ dtT,
                            int* __restrict__ flags) {
  unsigned i = blockIdx.x * 256u + threadIdx.x;
  if (i < 1966080u) {               // WbT[c][k] = bf16(W[k][c])
    unsigned c = i / 768u, k = i % 768u;
    WbT[i] = f2bf(W[(size_t)k * 2560u + c]);
    return;
  }
  i -= 1966080u;
  if (i < 25600u) { embB[i] = f2bf(emb[i]); return; }
  i -= 25600u;
  if (i < 57344u) {                 // WiT[c][k] = bf16(Wi[k][c]), pad c=100..111 with 0
    unsigned c = i / 512u, k = i % 512u;
    WiT[i] = f2bf(c < 100u ? Wi[(size_t)k * 100u + c] : 0.f);
    return;
  }
  i -= 57344u;
  if (i < 32768u) {                 // dtT[t][b] = td[b][t]
    unsigned t = i / 64u, b = i % 64u;
    dtT[i] = td[(size_t)b * 512u + t];
    return;
  }
  i -= 32768u;
  if (i < 65536u) { flags[i] = 0; return; }
}

// ---------------- zx = gather(embedding) @ W_x + b, stored bf16 in frag-permuted layout ----
__global__ __launch_bounds__(256, 2)
void zx_kernel(const int* __restrict__ evt, const unsigned short* __restrict__ embB,
               const unsigned short* __restrict__ WbT, const float* __restrict__ bias,
               unsigned short* __restrict__ zxp) {
  const int t = blockIdx.y;
  const int tid = threadIdx.x;
  const int v = tid >> 6, lane = tid & 63;
  const int m = lane & 15, quad = lane >> 4;
  const int cbase = blockIdx.x * 256 + v * 64;  // wave's 64 output cols (4 frags)

  s16x8 Breg[8][4];
#pragma unroll
  for (int cf = 0; cf < 4; ++cf) {
    const unsigned short* bp = WbT + (size_t)(cbase + cf * 16 + m) * 768 + quad * 8;
#pragma unroll
    for (int ch = 0; ch < 8; ++ch) Breg[ch][cf] = *(const s16x8*)(bp + ch * 32);
  }
  int ev[4];
#pragma unroll
  for (int rt = 0; rt < 4; ++rt) ev[rt] = evt[(size_t)(rt * 16 + m) * 512 + t];

  vf4 acc[4][4];
#pragma unroll
  for (int cf = 0; cf < 4; ++cf) {
    float bbv = bias[cbase + cf * 16 + m];
#pragma unroll
    for (int rt = 0; rt < 4; ++rt) acc[rt][cf] = (vf4){bbv, bbv, bbv, bbv};
  }
#pragma unroll
  for (int ch = 0; ch < 8; ++ch) {
#pragma unroll
    for (int rt = 0; rt < 4; ++rt) {
      s16x8 a = *(const s16x8*)(embB + (size_t)ev[rt] * 256 + ch * 32 + quad * 8);
#pragma unroll
      for (int cf = 0; cf < 4; ++cf)
        acc[rt][cf] = __builtin_amdgcn_mfma_f32_16x16x32_bf16(a, Breg[ch][cf], acc[rt][cf], 0, 0, 0);
    }
  }
#pragma unroll
  for (int cf = 0; cf < 4; ++cf) {
    int col0 = cbase + cf * 16;
    int g = col0 >> 9;              // gate index
    int w = (col0 & 511) >> 4;      // scan WG owning these cols
#pragma unroll
    for (int rt = 0; rt < 4; ++rt) {
      unsigned h0 = f2bf(acc[rt][cf][0]);
      unsigned h1 = f2bf(acc[rt][cf][1]);
      unsigned h2 = f2bf(acc[rt][cf][2]);
      unsigned h3 = f2bf(acc[rt][cf][3]);
      uint2 val;
      val.x = h0 | (h1 << 16);
      val.y = h2 | (h3 << 16);
      ((uint2*)zxp)[((((size_t)t * 32 + w) * 4 + rt) * 5 + g) * 64 + lane] = val;
    }
  }
}

// ---------------- persistent sequential scan: 32 WGs, wave-to-wave flag sync ----------------
// Wave v of WG w owns batch rows [16v,16v+16) x hidden cols [16w,16w+16).
// Protocol (R0-verified): sc1 h-stores -> waitcnt(0) -> agent flag store;
// consumers agent-poll flags, plain-load h (first-touch freshness).
// R5 structure retained (per-chunk consumption with done-mask).
// NEW vs R5: (a) coalesced flag layout — one poll instruction touches 2 L3 lines
// instead of 32 (16x less poll fabric traffic); (b) no s_sleep — the poll load's
// own ~600cy latency paces the spin, minimizing observe lag.
__global__ __launch_bounds__(256, 1)
void scan_kernel(const unsigned short* __restrict__ WbT,
                 const unsigned short* __restrict__ zxp,
                 const float* __restrict__ dtT,
                 unsigned short* __restrict__ hbuf,
                 int* __restrict__ flags,
                 float* __restrict__ out_h, float* __restrict__ out_d) {
  const int w = blockIdx.x;           // 0..31, owns hidden cols [w*16, w*16+16)
  const int tid = threadIdx.x;
  const int v = tid >> 6, lane = tid & 63;
  const int m = lane & 15, quad = lane >> 4;
  const int rowb = v * 16;
  const int bb0 = rowb + quad * 4;    // first batch row of this lane's C-frag elems
  const int col = w * 16 + m;         // hidden col of this lane's C-frag elems

  // W_h slice resident in registers: Breg[ch][g], k = 256 + ch*32 + quad*8 + j
  s16x8 Breg[16][5];
#pragma unroll
  for (int g = 0; g < 5; ++g) {
    const unsigned short* bp = WbT + (size_t)(g * 512 + w * 16 + m) * 768 + 256 + quad * 8;
#pragma unroll
    for (int ch = 0; ch < 16; ++ch) Breg[ch][g] = *(const s16x8*)(bp + ch * 32);
  }

  vf4 cst = (vf4){0.f, 0.f, 0.f, 0.f};   // cell state (4 rows x this lane's col)

  for (int t = 0; t < 512; ++t) {
    // acc init from zx (independent of recurrence -> issued before any wait)
    vf4 acc[5];
#pragma unroll
    for (int g = 0; g < 5; ++g) {
      uint2 zv = ((const uint2*)zxp)[((((size_t)t * 32 + w) * 4 + v) * 5 + g) * 64 + lane];
      acc[g][0] = bf2f((unsigned short)(zv.x & 0xffffu));
      acc[g][1] = bf2f((unsigned short)(zv.x >> 16));
      acc[g][2] = bf2f((unsigned short)(zv.y & 0xffffu));
      acc[g][3] = bf2f((unsigned short)(zv.y >> 16));
    }
    vf4 dt4 = *(const vf4*)(dtT + t * 64 + bb0);

    if (t > 0) {
      const int tp = t - 1;
      const unsigned short* hsrc =
          hbuf + (size_t)tp * (BB * HH) + (size_t)(rowb + m) * HH + quad * 8;
      const int* fbase = flags + fidx(tp, v, 0);
      // done bit L = producer WG L (wave v) has published h[tp].
      unsigned long long done = 0;
      s16x8 areg[16];                 // fully-unrolled chunk pipeline -> static indices
#pragma unroll
      for (int ch = 0; ch < 16; ++ch) {
        const unsigned long long need = 3ull << (2 * ch);
        while ((done & need) != need) {
          int f = 0;
          if (lane < 32 && !((done >> lane) & 1ull))
            f = __hip_atomic_load(fbase + lane, __ATOMIC_RELAXED,
                                  __HIP_MEMORY_SCOPE_AGENT);   // ONE coalesced 128B poll
          done |= __ballot(f != 0);
        }
        // Compiler barrier: the chunk load must not be hoisted above the flag
        // observation (same ordering argument as the verified base protocol).
        __asm__ __volatile__("" ::: "memory");
        areg[ch] = *(const s16x8*)(hsrc + ch * 32);   // in flight under MFMAs below
        if (ch > 0) {
#pragma unroll
          for (int g = 0; g < 5; ++g)
            acc[g] = __builtin_amdgcn_mfma_f32_16x16x32_bf16(areg[ch - 1], Breg[ch - 1][g],
                                                             acc[g], 0, 0, 0);
        }
      }
#pragma unroll
      for (int g = 0; g < 5; ++g)
        acc[g] = __builtin_amdgcn_mfma_f32_16x16x32_bf16(areg[15], Breg[15][g],
                                                         acc[g], 0, 0, 0);
    }

    // gates + state update; publish h (sc1, coherence point) on the critical path,
    // fp32 outputs deferred until after the flag store.
    float hv[4], dv[4];
#pragma unroll
    for (int r = 0; r < 4; ++r) {
      float i_ = sigmoidf_(acc[0][r]);
      float f_ = sigmoidf_(acc[1][r]);
      float o_ = sigmoidf_(acc[2][r]);
      float g_ = tanhf_(acc[3][r]);
      float dec = softplusf_(acc[4][r]);
      float cn = f_ * cst[r] + i_ * g_;
      float ct = cn * __expf(-dec * dt4[r]);
      float h_ = o_ * tanhf_(ct);
      cst[r] = ct;
      hv[r] = h_; dv[r] = dec;
      __hip_atomic_store(hbuf + (size_t)t * (BB * HH) + (size_t)(bb0 + r) * HH + col,
                         f2bf(h_), __ATOMIC_RELAXED, __HIP_MEMORY_SCOPE_AGENT);
    }
    // Drain this wave's sc1 h-stores, then publish. (Manual waitcnt instead of a
    // RELEASE store to avoid a possible buffer_wbl2 in the atomic-release lowering.)
    __asm__ __volatile__("" ::: "memory");
    __builtin_amdgcn_s_waitcnt(0);
    __asm__ __volatile__("" ::: "memory");
    if (lane == 0) {
      __hip_atomic_store(flags + fidx(t, v, w), 1, __ATOMIC_RELAXED,
                         __HIP_MEMORY_SCOPE_AGENT);
    }
    // Off-critical-path fp32 outputs (drained by next step's waitcnt, overlapped).
#pragma unroll
    for (int r = 0; r < 4; ++r) {
      size_t oo = ((size_t)(bb0 + r) * SS + t) * HH + col;
      out_h[oo] = hv[r];
      out_d[oo] = dv[r];
    }
  }
}

// ---------------- base_intensities = softplus(h @ Wi + bi) ----------------
__global__ __launch_bounds__(256, 2)
void inten_kernel(const unsigned short* __restrict__ hbuf,
                  const unsigned short* __restrict__ WiT,
                  const float* __restrict__ bi,
                  float* __restrict__ out_i) {
  const int b = blockIdx.y;            // batch row
  const int t0 = blockIdx.x * 64;      // 64 timesteps per WG
  const int tid = threadIdx.x;
  const int v = tid >> 6, lane = tid & 63;
  const int m = lane & 15, quad = lane >> 4;
  const int trow = t0 + v * 16 + m;    // A row = timestep

  vf4 acc[7];
#pragma unroll
  for (int cf = 0; cf < 7; ++cf) {
    int c = cf * 16 + m;
    float bbv = (c < 100) ? bi[c] : 0.f;
    acc[cf] = (vf4){bbv, bbv, bbv, bbv};
  }
  const unsigned short* ha = hbuf + ((size_t)trow * 64 + b) * 512 + quad * 8;
#pragma unroll 4
  for (int ch = 0; ch < 16; ++ch) {
    s16x8 a = *(const s16x8*)(ha + ch * 32);
#pragma unroll
    for (int cf = 0; cf < 7; ++cf) {
      s16x8 bf = *(const s16x8*)(WiT + (size_t)(cf * 16 + m) * 512 + ch * 32 + quad * 8);
      acc[cf] = __builtin_amdgcn_mfma_f32_16x16x32_bf16(a, bf, acc[cf], 0, 0, 0);
    }
  }
#pragma unroll
  for (int cf = 0; cf < 7; ++cf) {
    int c = cf * 16 + m;
#pragma unroll
    for (int r = 0; r < 4; ++r) {
      int tt = t0 + v * 16 + quad * 4 + r;
      if (c < 100) out_i[((size_t)b * 512 + tt) * 100 + c] = softplusf_(acc[cf][r]);
    }
  }
}

extern "C" void kernel_launch(void* const* d_in, const int* in_sizes, int n_in,
                              void* d_out, int out_size, void* d_ws, size_t ws_size,
                              hipStream_t stream) {
  (void)in_sizes; (void)n_in; (void)out_size; (void)ws_size;
  const int*   evt  = (const int*)d_in[0];
  const float* td   = (const float*)d_in[1];
  const float* emb  = (const float*)d_in[2];
  const float* W    = (const float*)d_in[3];
  const float* bias = (const float*)d_in[4];
  const float* Wi   = (const float*)d_in[5];
  const float* bi   = (const float*)d_in[6];

  char* ws = (char*)d_ws;
  unsigned short* WbT  = (unsigned short*)(ws + OFF_WBT);
  unsigned short* embB = (unsigned short*)(ws + OFF_EMB);
  unsigned short* WiT  = (unsigned short*)(ws + OFF_WIT);
  float*          dtT  = (float*)(ws + OFF_DTT);
  int*            flags= (int*)(ws + OFF_FLAGS);
  unsigned short* hbuf = (unsigned short*)(ws + OFF_HBUF);
  unsigned short* zxp  = (unsigned short*)(ws + OFF_ZXP);

  float* out_h = (float*)d_out;
  float* out_d = out_h + (size_t)BB * SS * HH;
  float* out_i = out_d + (size_t)BB * SS * HH;

  init_kernel<<<8388, 256, 0, stream>>>(W, emb, Wi, td, WbT, embB, WiT, dtT, flags);
  zx_kernel<<<dim3(10, 512), 256, 0, stream>>>(evt, embB, WbT, bias, zxp);
  scan_kernel<<<NWG, 256, 0, stream>>>(WbT, zxp, dtT, hbuf, flags, out_h, out_d);
  inten_kernel<<<dim3(8, 64), 256, 0, stream>>>(hbuf, WiT, bi, out_i);
}